// Round 16
// baseline (140.103 us; speedup 1.0000x reference)
//
#include <hip/hip_runtime.h>
#include <math.h>

#define NPTS 8192
#define NB 2
#define NROWS (NB * NPTS)
#define KNN 16
#define KC 6          // per-lane kept candidates (truncated sorted list)

// Spatial grid: 32^3 cells of width H. 4 grids: P/T x batch. g: P=2b, T=2b+1.
// H=0.28 (R16): halves shell-1 candidate volume vs 0.35; range +-4.48 covers
// N(0,1) to ~1 clamped point/launch (clamping is correctness-safe: a clamped
// point's true position is farther than its cell implies, so the unvisited-
// cell bound stays valid).
#define GRID 32
#define NCELLS (GRID * GRID * GRID)        // 32768
#define TOTCELLS (4 * NCELLS)              // 131072
#define H 0.28f
#define RLO (-4.48f)
#define INVH (1.0f / H)
#define SCAN_BLOCKS 128
#define SEGCAP 132                          // >= 2*64 segments per row-chunk

__device__ __forceinline__ int cellof(float x) {
  int c = (int)floorf((x - RLO) * INVH);
  return min(max(c, 0), GRID - 1);
}

__device__ __forceinline__ float sqd3(float qx, float qy, float qz, float4 c) {
  float dx = qx - c.x, dy = qy - c.y, dz = qz - c.z;
  return fmaf(dx, dx, fmaf(dy, dy, dz * dz));
}

__device__ __forceinline__ int lanerank(unsigned long long mk) {
  return __builtin_amdgcn_mbcnt_hi((unsigned)(mk >> 32),
                                   __builtin_amdgcn_mbcnt_lo((unsigned)mk, 0));
}

// Guarded insert into ascending sorted-K list (per-lane).
template <int K>
__device__ __forceinline__ void insertK(float (&a)[K], float d) {
  if (d < a[K - 1]) {
    a[K - 1] = d;
#pragma unroll
    for (int k = K - 1; k > 0; --k) {
      float lo = fminf(a[k - 1], a[k]);
      a[k] = fmaxf(a[k - 1], a[k]);
      a[k - 1] = lo;
    }
  }
}

// Full ascending bitonic sort of one value per lane across the 64-lane wave.
__device__ __forceinline__ float bitonic_sort64(float v, int lane) {
#pragma unroll
  for (int k = 2; k <= 64; k <<= 1) {
#pragma unroll
    for (int j = k >> 1; j >= 1; j >>= 1) {
      float o = __shfl_xor(v, j, 64);
      bool up = ((lane & k) == 0);
      bool lower = ((lane & j) == 0);
      float mn = fminf(v, o), mx = fmaxf(v, o);
      v = (up == lower) ? mn : mx;
    }
  }
  return v;
}

// Wave-cooperative kNN for ONE query (one query per wave -- this problem is
// latency-bound; wave count is the thing to protect [R5/R6/R11 lesson]),
// via expanding Chebyshev shells on a counting-sorted grid.
// Exactness: after completing shell m, an unvisited cell has per-axis index
// gap >= m+1 from the query's cell, so its points are > (m*H + fq) from the
// query, fq = min per-axis in-cell slack (clamped to >= 0 for out-of-range
// queries -- conservative). 0.999 covers float binning boundary error
// (~1e-7 << 3.4e-3 threshold); clamped cells only increase true distances.
// dmin = min value ever evicted from this lane's list (INF while not full)
// -> exact truncation-loss test by caller. Stop when >= NEED kept candidates
// lie within the bound (undercount -> conservative). cnt/bnd2 returned from
// the final stop test for the caller's cheap compaction threshold.
template <int K, int NEED>
__device__ void wave_grid_knn(int g, float qx, float qy, float qz,
                              const float4* __restrict__ sorted,
                              const unsigned* __restrict__ pack,
                              unsigned* sS, unsigned* sC, unsigned* sPre,
                              int lane, float (&a)[K], float& dmin,
                              int& cnt, float& bnd2) {
  const int cx = cellof(qx), cy = cellof(qy), cz = cellof(qz);
  float fx = fminf(qx - (RLO + cx * H), (RLO + (cx + 1) * H) - qx);
  float fy = fminf(qy - (RLO + cy * H), (RLO + (cy + 1) * H) - qy);
  float fz = fminf(qz - (RLO + cz * H), (RLO + (cz + 1) * H) - qz);
  const float fq = fminf(fx, fminf(fy, fz));   // may be <0 for clamped queries
  const int base = g * NCELLS;
  for (int m = 0; m <= GRID; ++m) {
    const int zlo = max(cz - m, 0), zhi = min(cz + m, GRID - 1);
    const int ylo = max(cy - m, 0), yhi = min(cy + m, GRID - 1);
    const int xlo = max(cx - m, 0), xhi = min(cx + m, GRID - 1);
    const int ny = yhi - ylo + 1;
    const int nrows = (zhi - zlo + 1) * ny;
    for (int rb = 0; rb < nrows; rb += 64) {
      const int rho = rb + lane;
      const bool act = rho < nrows;
      const int rr = act ? rho : 0;
      const int z = zlo + rr / ny, y = ylo + rr % ny;
      const int dza = abs(z - cz), dya = abs(y - cy);
      const bool bdry = (dza == m) || (dya == m);
      unsigned stA = 0, cnA = 0, stB = 0, cnB = 0;
      const int rowbase = base + (z * GRID + y) * GRID;
      if (act) {
        if (bdry) {  // full (clamped) x-range: contiguous segment, 2 loads
          unsigned plo = pack[rowbase + xlo];
          unsigned phi = pack[rowbase + xhi];
          stA = plo >> 14;
          cnA = ((phi >> 14) + (phi & 16383u)) - stA;
        } else {     // interior row: only the two new x = cx +- m cells
          int xl = cx - m, xr = cx + m;
          if (xl >= 0) { unsigned p = pack[rowbase + xl]; stA = p >> 14; cnA = p & 16383u; }
          if (xr < GRID) { unsigned p = pack[rowbase + xr]; stB = p >> 14; cnB = p & 16383u; }
        }
      }
      // ballot-compact nonempty segments into wave-private LDS
      unsigned long long mA = __ballot(cnA > 0);
      unsigned long long mB = __ballot(cnB > 0);
      int nA = __popcll(mA);
      int nseg = nA + __popcll(mB);
      if (nseg == 0) continue;
      int slA = lanerank(mA), slB = nA + lanerank(mB);
      if (cnA > 0) { sS[slA] = stA; sC[slA] = cnA; }
      if (cnB > 0) { sS[slB] = stB; sC[slB] = cnB; }
      // exclusive prefix over segment counts (<=128 segs, 2 halves of 64)
      unsigned total = 0;
      for (int h = 0; h < 2; ++h) {
        int sl = h * 64 + lane;
        unsigned v = (sl < nseg) ? sC[sl] : 0u;
        unsigned inc = v;
#pragma unroll
        for (int s2 = 1; s2 < 64; s2 <<= 1) {
          unsigned t = __shfl_up(inc, s2, 64);
          if (lane >= s2) inc += t;
        }
        if (sl < nseg) sPre[sl] = total + inc - v;
        total += __shfl(inc, 63, 64);
        if (nseg <= 64) break;
      }
      // candidates 64-wide across segment boundaries; depth-adaptive search
      int sh0 = (nseg > 1) ? (1 << (31 - __clz(nseg - 1))) : 0;
      for (unsigned cb = 0; cb < total; cb += 64) {
        unsigned c = cb + (unsigned)lane;
        bool cact = c < total;
        unsigned cc = cact ? c : (total - 1);
        int lo = 0;  // max seg with sPre[seg] <= cc (sPre[0]==0)
        for (int sh = sh0; sh; sh >>= 1) {
          int mid = lo + sh;
          if (mid < nseg && sPre[mid] <= cc) lo = mid;
        }
        float4 p = sorted[sS[lo] + (cc - sPre[lo])];
        float d = cact ? sqd3(qx, qy, qz, p) : INFINITY;
        dmin = fminf(dmin, fmaxf(d, a[K - 1]));  // exact evicted-value track
        insertK(a, d);
      }
    }
    // stop test: >= NEED kept candidates within the (tight) bound?
    float bnd = fmaxf((float)m * H + fq, 0.0f) * 0.999f;
    bnd2 = bnd * bnd;
    int c = 0;
#pragma unroll
    for (int k = 0; k < K; ++k) c += (a[k] <= bnd2) ? 1 : 0;
#pragma unroll
    for (int s2 = 1; s2 < 64; s2 <<= 1) c += __shfl_xor(c, s2, 64);
    cnt = c;
    bool covered = (zlo == 0 && zhi == GRID - 1 && ylo == 0 && yhi == GRID - 1 &&
                    xlo == 0 && xhi == GRID - 1);
    if (c >= NEED || covered) break;
  }
}

// ---------- build ----------
// Histogram + per-point (cell, rank): rank from the returning atomic makes
// the scatter atomic-free.
__global__ __launch_bounds__(256) void count_kernel(
    const float* __restrict__ yp, const float* __restrict__ yt,
    unsigned* __restrict__ counts, int* __restrict__ pflat,
    unsigned* __restrict__ prank) {
  int t = blockIdx.x * 256 + threadIdx.x;          // 0 .. 2*NROWS-1
  const float* src;
  int g;
  if (t < NROWS) { src = yp + 3 * t; g = 2 * (t >> 13); }
  else { int u = t - NROWS; src = yt + 3 * u; g = 2 * (u >> 13) + 1; }
  int flat = g * NCELLS + (cellof(src[2]) * GRID + cellof(src[1])) * GRID + cellof(src[0]);
  unsigned r = atomicAdd(&counts[flat], 1u);
  pflat[t] = flat;
  prank[t] = r;
}

// Block-level exclusive scan via wave shfl_up scans (barrier count: 2).
__global__ __launch_bounds__(1024) void scan1_kernel(
    const unsigned* __restrict__ counts, unsigned* __restrict__ partial,
    unsigned* __restrict__ aux) {
  __shared__ unsigned ws[16];
  const int t = threadIdx.x, lane = t & 63, wave = t >> 6;
  const int tid = blockIdx.x * 1024 + t;
  unsigned v = counts[tid];
  unsigned inc = v;                       // inclusive scan within wave
#pragma unroll
  for (int off = 1; off < 64; off <<= 1) {
    unsigned u = __shfl_up(inc, off, 64);
    if (lane >= off) inc += u;
  }
  if (lane == 63) ws[wave] = inc;         // wave totals
  __syncthreads();
  unsigned wex = 0;                       // exclusive scan of 16 wave totals
  if (wave == 0) {
    unsigned o = (lane < 16) ? ws[lane] : 0u;
    unsigned wi = o;
#pragma unroll
    for (int off = 1; off < 16; off <<= 1) {
      unsigned u = __shfl_up(wi, off, 64);
      if (lane >= off) wi += u;
    }
    if (lane < 16) ws[lane] = wi - o;
  }
  __syncthreads();
  wex = ws[wave];
  partial[tid] = wex + inc - v;           // block-exclusive
  if (t == 1023) aux[blockIdx.x] = wex + inc;  // block total
}

// Fused pack+scatter. Wave 0 shuffle-scans the 128 aux block-totals ONCE
// into an LDS exclusive prefix (O(1) lookups afterwards). Thread t packs
// cells 4t..4t+3 and scatters point t; its slot start is derived from
// partial/aux directly, independent of the pack array it writes.
__global__ __launch_bounds__(256) void scatter_kernel(
    const float* __restrict__ yp, const float* __restrict__ yt,
    const unsigned* __restrict__ counts, const unsigned* __restrict__ partial,
    const unsigned* __restrict__ aux, const int* __restrict__ pflat,
    const unsigned* __restrict__ prank, unsigned* __restrict__ pack,
    float4* __restrict__ sorted) {
  __shared__ unsigned pre[SCAN_BLOCKS];   // exclusive prefix of aux
  const int t = blockIdx.x * 256 + threadIdx.x;   // 0 .. 2*NROWS-1
  const int lane = threadIdx.x & 63;
  if ((threadIdx.x >> 6) == 0) {          // wave 0: scan 128 totals (2 halves)
    unsigned a0 = aux[lane], a1 = aux[64 + lane];
    unsigned i0 = a0, i1 = a1;
#pragma unroll
    for (int off = 1; off < 64; off <<= 1) {
      unsigned u0 = __shfl_up(i0, off, 64);
      unsigned u1 = __shfl_up(i1, off, 64);
      if (lane >= off) { i0 += u0; i1 += u1; }
    }
    unsigned tot0 = __shfl(i0, 63, 64);
    pre[lane] = i0 - a0;
    pre[64 + lane] = tot0 + i1 - a1;
  }
  __syncthreads();
  // pack 4 contiguous cells (their aux block == blockIdx.x: uniform)
  const int c0 = t * 4;
  const unsigned apre = pre[c0 >> 10];
#pragma unroll
  for (int j = 0; j < 4; ++j) {
    int c = c0 + j;
    pack[c] = ((partial[c] + apre) << 14) | counts[c];
  }
  // scatter own point
  const float* src;
  int row;
  if (t < NROWS) { row = t; src = yp + 3 * t; }
  else { row = t - NROWS; src = yt + 3 * row; }
  const int flat = pflat[t];
  unsigned pos = partial[flat] + pre[flat >> 10] + prank[t];
  sorted[pos] = make_float4(src[0], src[1], src[2], __int_as_float(row));
}

// ---------- queries: one wave per query, spatially-sorted order ----------
// wid [0,16384): T point vs P grid  -> knnP row (16 sqrt'd dists) + flag
// wid [16384,32768): T vs T grid    -> knnT row (self included) + flag
// wid [32768,49152): P vs T grid    -> mincol (exact, no flag)
__global__ __launch_bounds__(256) void query_kernel(
    const float4* __restrict__ sorted, const unsigned* __restrict__ pack,
    float* __restrict__ knnP, float* __restrict__ knnT,
    float* __restrict__ mincol_arr, unsigned* __restrict__ flags) {
  __shared__ unsigned sb[4][3][SEGCAP];
  __shared__ float cbw[4][64];
  const int wave = threadIdx.x >> 6, lane = threadIdx.x & 63;
  const int wid = blockIdx.x * 4 + wave;
  const int type = wid >> 14;
  const int qid = wid & 16383;
  const int b = qid >> 13;
  const int src_g = (type == 2) ? 2 * b : 2 * b + 1;
  const int tgt_g = (type == 0) ? 2 * b : 2 * b + 1;
  float4 e = sorted[src_g * NPTS + (qid & (NPTS - 1))];
  const int row = __float_as_int(e.w);
  unsigned* sS = sb[wave][0];
  unsigned* sC = sb[wave][1];
  unsigned* sP = sb[wave][2];
  float* cbuf = cbw[wave];
  if (type < 2) {
    float a[KC];
#pragma unroll
    for (int k = 0; k < KC; ++k) a[k] = INFINITY;
    float dmin = INFINITY, bnd2;
    int cnt;
    wave_grid_knn<KC, KNN>(tgt_g, e.x, e.y, e.z, sorted, pack, sS, sC, sP,
                           lane, a, dmin, cnt, bnd2);
    // Compaction threshold tau (must be >= true v16, with <=64 kept <= tau):
    // cheap path = the verified stop bound when its count is in [16,64];
    // else 16th-smallest lane-min (lane minima are never truncated away).
    float tau;
    if (cnt >= KNN && cnt <= 64) {
      tau = bnd2;
    } else {
      float slm = bitonic_sort64(a[0], lane);
      tau = __shfl(slm, 15, 64);
    }
    int tot = 0;
    int idx[KC];
#pragma unroll
    for (int k = 0; k < KC; ++k) {
      unsigned long long mk = __ballot(a[k] <= tau);
      idx[k] = tot + lanerank(mk);
      tot += __popcll(mk);
    }
#pragma unroll
    for (int k = 0; k < KC; ++k)
      if (a[k] <= tau && idx[k] < 64) cbuf[idx[k]] = a[k];
    float v = (lane < tot) ? cbuf[lane] : INFINITY;  // same-wave: no barrier
    v = bitonic_sort64(v, lane);
    float f15 = __shfl(v, 15, 64);
    // EXACT validity: a lost top-16 member implies dmin <= v16_true <= f15.
    bool bad = (tot > 64) || (__ballot(dmin <= f15) != 0ull);
    float* dst = (type == 0) ? knnP : knnT;
    if (lane < KNN) dst[row * KNN + lane] = sqrtf(v);
    if (lane == 0) flags[type * NROWS + row] = bad ? 1u : 0u;
  } else {
    float a1[1] = {INFINITY};
    float dmin = INFINITY, bnd2;
    int cnt;
    wave_grid_knn<1, 1>(tgt_g, e.x, e.y, e.z, sorted, pack, sS, sC, sP,
                        lane, a1, dmin, cnt, bnd2);
    float v = a1[0];
#pragma unroll
    for (int s = 1; s < 64; s <<= 1) v = fminf(v, __shfl_xor(v, s, 64));
    if (lane == 0) mincol_arr[row] = sqrtf(v);  // lane minima exact
  }
}

// Guaranteed-exact dense fallback over one grid slice (8192 points):
// lane r (r<16) returns the r-th smallest squared distance.
__device__ float exact16_rowlist(const float4* __restrict__ base,
                                 float qx, float qy, float qz, int lane) {
  float a[KNN];
#pragma unroll
  for (int k = 0; k < KNN; ++k) a[k] = INFINITY;
  for (int s = 0; s < NPTS / 64; ++s) {
    float d = sqd3(qx, qy, qz, base[s * 64 + lane]);
    insertK(a, d);
  }
  float res = INFINITY;
#pragma unroll 1
  for (int r = 0; r < KNN; ++r) {
    float v = a[0];
    int idx = lane;
#pragma unroll
    for (int s = 1; s < 64; s <<= 1) {
      float ov = __shfl_xor(v, s, 64);
      int oi = __shfl_xor(idx, s, 64);
      bool take = (ov < v) || (ov == v && oi < idx);
      v = take ? ov : v;
      idx = take ? oi : idx;
    }
    if (lane == r) res = v;
    if (lane == idx) {
#pragma unroll
      for (int k = 0; k < KNN - 1; ++k) a[k] = a[k + 1];
      a[KNN - 1] = INFINITY;
    }
  }
  return res;
}

// Fused tail+combine+finalize: each wave repairs flagged rows among its 64
// rows (expected ~0 per launch), the block computes deterministic double
// partials, and the LAST finished block (device-scope ticket; no barrier,
// no co-residency assumption) reduces all 64 partials in fixed order.
__global__ __launch_bounds__(256) void combine_kernel(
    const float* __restrict__ yt, const float4* __restrict__ sorted,
    const unsigned* __restrict__ flags, float* __restrict__ knnP,
    float* __restrict__ knnT, const float* __restrict__ mincol_arr,
    double* __restrict__ pd, unsigned* __restrict__ ticket,
    float* __restrict__ out) {
  __shared__ double s1[256], s2[256], s3[256];
  __shared__ unsigned oldv;
  const int t = threadIdx.x, lane = t & 63, wave = t >> 6;
  const int row0 = blockIdx.x * 256;
  const int rbase = row0 + wave * 64;
  unsigned f0 = flags[rbase + lane];
  unsigned f1 = flags[NROWS + rbase + lane];
  unsigned long long m0 = __ballot(f0 != 0u);
  unsigned long long m1 = __ballot(f1 != 0u);
  while (m0) {                                        // wave-uniform loop
    int rr = __ffsll(m0) - 1; m0 &= m0 - 1;
    int row = rbase + rr;
    int bb = row >> 13;
    const float* q = yt + 3 * row;
    float s = exact16_rowlist(sorted + (size_t)(2 * bb) * NPTS, q[0], q[1], q[2], lane);
    if (lane < KNN) knnP[row * KNN + lane] = sqrtf(s);
  }
  while (m1) {
    int rr = __ffsll(m1) - 1; m1 &= m1 - 1;
    int row = rbase + rr;
    int bb = row >> 13;
    const float* q = yt + 3 * row;
    float s = exact16_rowlist(sorted + (size_t)(2 * bb + 1) * NPTS, q[0], q[1], q[2], lane);
    if (lane < KNN) knnT[row * KNN + lane] = sqrtf(s);
  }
  __syncthreads();  // repairs (global writes by this block) visible block-wide
  const int row = row0 + t;
  float s = 0.0f;
#pragma unroll
  for (int k = 0; k < KNN; ++k)
    s += fabsf(knnP[row * KNN + k] - knnT[row * KNN + k]);
  s1[t] = (double)knnP[row * KNN];   // minrow
  s2[t] = (double)mincol_arr[row];
  s3[t] = (double)s;
  __syncthreads();
  for (int off = 128; off > 0; off >>= 1) {
    if (t < off) { s1[t] += s1[t + off]; s2[t] += s2[t + off]; s3[t] += s3[t + off]; }
    __syncthreads();
  }
  if (t == 0) {
    pd[blockIdx.x * 3 + 0] = s1[0];
    pd[blockIdx.x * 3 + 1] = s2[0];
    pd[blockIdx.x * 3 + 2] = s3[0];
  }
  // last-done block finalizes (deterministic: fixed-order read of pd[0..63])
  __threadfence();
  if (t == 0) oldv = atomicAdd(ticket, 1u);
  __syncthreads();
  if (oldv == 63) {
    __threadfence();
    if (t < 64) {
      const volatile double* vpd = (const volatile double*)pd;
      double a = vpd[t * 3], b = vpd[t * 3 + 1], c = vpd[t * 3 + 2];
#pragma unroll
      for (int s2 = 32; s2 >= 1; s2 >>= 1) {
        a += __shfl_down(a, s2, 64);
        b += __shfl_down(b, s2, 64);
        c += __shfl_down(c, s2, 64);
      }
      if (t == 0) {
        double shape = 0.5 * (a + b) / (double)NROWS;
        double dens = c / ((double)NROWS * KNN);
        out[0] = (float)(shape + dens);
        out[1] = (float)shape;
        out[2] = (float)dens;
      }
    }
  }
}

extern "C" void kernel_launch(void* const* d_in, const int* in_sizes, int n_in,
                              void* d_out, int out_size, void* d_ws, size_t ws_size,
                              hipStream_t stream) {
  (void)in_sizes; (void)n_in; (void)out_size; (void)ws_size;
  const float* yp = (const float*)d_in[0];  // y_pred [B, N, 3]
  const float* yt = (const float*)d_in[1];  // y_true [B, N, 3]
  char* w = (char*)d_ws;
  unsigned* counts  = (unsigned*)w;  w += TOTCELLS * 4;     // 512 KB (memset 0)
  unsigned* ticket  = (unsigned*)w;  w += 64;               // rides the memset
  unsigned* partial = (unsigned*)w;  w += TOTCELLS * 4;     // 512 KB
  unsigned* aux     = (unsigned*)w;  w += 512;
  unsigned* pack    = (unsigned*)w;  w += TOTCELLS * 4;     // 512 KB
  int*      pflat   = (int*)w;       w += 2 * NROWS * 4;    // 128 KB
  unsigned* prank   = (unsigned*)w;  w += 2 * NROWS * 4;    // 128 KB
  float4*   sorted  = (float4*)w;    w += 2 * NROWS * 16;   // 1 MB
  float*    knnP    = (float*)w;     w += NROWS * KNN * 4;  // 1 MB
  float*    knnT    = (float*)w;     w += NROWS * KNN * 4;  // 1 MB
  float*    mincol  = (float*)w;     w += NROWS * 4;
  unsigned* flags   = (unsigned*)w;  w += 2 * NROWS * 4;    // written every launch
  double*   pd      = (double*)w;    w += 64 * 3 * 8;
  float* out = (float*)d_out;

  hipMemsetAsync(counts, 0, (size_t)TOTCELLS * 4 + 64, stream);  // counts+ticket
  count_kernel<<<2 * NROWS / 256, 256, 0, stream>>>(yp, yt, counts, pflat, prank);
  scan1_kernel<<<SCAN_BLOCKS, 1024, 0, stream>>>(counts, partial, aux);
  scatter_kernel<<<2 * NROWS / 256, 256, 0, stream>>>(yp, yt, counts, partial, aux,
                                                      pflat, prank, pack, sorted);
  query_kernel<<<3 * 16384 / 4, 256, 0, stream>>>(sorted, pack, knnP, knnT, mincol, flags);
  combine_kernel<<<64, 256, 0, stream>>>(yt, sorted, flags, knnP, knnT, mincol,
                                         pd, ticket, out);
}

// Round 17
// 137.187 us; speedup vs baseline: 1.0213x; 1.0213x over previous
//
#include <hip/hip_runtime.h>
#include <math.h>

#define NPTS 8192
#define NB 2
#define NROWS (NB * NPTS)
#define KNN 16
#define KC 6          // per-lane kept candidates (truncated sorted list)

// Spatial grid: 32^3 cells of width H. 4 grids: P/T x batch. g: P=2b, T=2b+1.
// H=0.35 (R12 best; R16's H=0.28 was neutral-to-worse).
#define GRID 32
#define NCELLS (GRID * GRID * GRID)        // 32768
#define TOTCELLS (4 * NCELLS)              // 131072
#define H 0.35f
#define RLO (-5.6f)
#define INVH (1.0f / H)
#define SCAN_BLOCKS 128
#define SEGCAP 132                          // >= 2*64 segments per row-chunk

__device__ __forceinline__ int cellof(float x) {
  int c = (int)floorf((x - RLO) * INVH);
  return min(max(c, 0), GRID - 1);
}

__device__ __forceinline__ float sqd3(float qx, float qy, float qz, float4 c) {
  float dx = qx - c.x, dy = qy - c.y, dz = qz - c.z;
  return fmaf(dx, dx, fmaf(dy, dy, dz * dz));
}

__device__ __forceinline__ int lanerank(unsigned long long mk) {
  return __builtin_amdgcn_mbcnt_hi((unsigned)(mk >> 32),
                                   __builtin_amdgcn_mbcnt_lo((unsigned)mk, 0));
}

// Guarded insert into ascending sorted-K list (per-lane).
template <int K>
__device__ __forceinline__ void insertK(float (&a)[K], float d) {
  if (d < a[K - 1]) {
    a[K - 1] = d;
#pragma unroll
    for (int k = K - 1; k > 0; --k) {
      float lo = fminf(a[k - 1], a[k]);
      a[k] = fmaxf(a[k - 1], a[k]);
      a[k - 1] = lo;
    }
  }
}

// Full ascending bitonic sort of one value per lane across the 64-lane wave.
__device__ __forceinline__ float bitonic_sort64(float v, int lane) {
#pragma unroll
  for (int k = 2; k <= 64; k <<= 1) {
#pragma unroll
    for (int j = k >> 1; j >= 1; j >>= 1) {
      float o = __shfl_xor(v, j, 64);
      bool up = ((lane & k) == 0);
      bool lower = ((lane & j) == 0);
      float mn = fminf(v, o), mx = fmaxf(v, o);
      v = (up == lower) ? mn : mx;
    }
  }
  return v;
}

// Wave-cooperative kNN for ONE query (one query per wave -- this problem is
// latency-bound; wave count is the thing to protect [R5/R6/R11 lesson]),
// via expanding Chebyshev shells on a counting-sorted grid.
// Exactness: after completing shell m, an unvisited cell has per-axis index
// gap >= m+1 from the query's cell, so its points are > (m*H + fq) from the
// query, fq = min per-axis in-cell slack (clamped to >= 0 for out-of-range
// queries -- conservative). 0.999 covers float binning boundary error
// (~1e-7 << 3.4e-3 threshold); clamped cells only increase true distances.
// dmin = min value ever evicted from this lane's list (INF while not full)
// -> exact truncation-loss test by caller. Stop when >= NEED kept candidates
// lie within the bound (undercount -> conservative). cnt/bnd2 returned from
// the final stop test for the caller's cheap compaction threshold.
template <int K, int NEED>
__device__ void wave_grid_knn(int g, float qx, float qy, float qz,
                              const float4* __restrict__ sorted,
                              const unsigned* __restrict__ pack,
                              unsigned* sS, unsigned* sC, unsigned* sPre,
                              int lane, float (&a)[K], float& dmin,
                              int& cnt, float& bnd2) {
  const int cx = cellof(qx), cy = cellof(qy), cz = cellof(qz);
  float fx = fminf(qx - (RLO + cx * H), (RLO + (cx + 1) * H) - qx);
  float fy = fminf(qy - (RLO + cy * H), (RLO + (cy + 1) * H) - qy);
  float fz = fminf(qz - (RLO + cz * H), (RLO + (cz + 1) * H) - qz);
  const float fq = fminf(fx, fminf(fy, fz));   // may be <0 for clamped queries
  const int base = g * NCELLS;
  for (int m = 0; m <= GRID; ++m) {
    const int zlo = max(cz - m, 0), zhi = min(cz + m, GRID - 1);
    const int ylo = max(cy - m, 0), yhi = min(cy + m, GRID - 1);
    const int xlo = max(cx - m, 0), xhi = min(cx + m, GRID - 1);
    const int ny = yhi - ylo + 1;
    const int nrows = (zhi - zlo + 1) * ny;
    for (int rb = 0; rb < nrows; rb += 64) {
      const int rho = rb + lane;
      const bool act = rho < nrows;
      const int rr = act ? rho : 0;
      const int z = zlo + rr / ny, y = ylo + rr % ny;
      const int dza = abs(z - cz), dya = abs(y - cy);
      const bool bdry = (dza == m) || (dya == m);
      unsigned stA = 0, cnA = 0, stB = 0, cnB = 0;
      const int rowbase = base + (z * GRID + y) * GRID;
      if (act) {
        if (bdry) {  // full (clamped) x-range: contiguous segment, 2 loads
          unsigned plo = pack[rowbase + xlo];
          unsigned phi = pack[rowbase + xhi];
          stA = plo >> 14;
          cnA = ((phi >> 14) + (phi & 16383u)) - stA;
        } else {     // interior row: only the two new x = cx +- m cells
          int xl = cx - m, xr = cx + m;
          if (xl >= 0) { unsigned p = pack[rowbase + xl]; stA = p >> 14; cnA = p & 16383u; }
          if (xr < GRID) { unsigned p = pack[rowbase + xr]; stB = p >> 14; cnB = p & 16383u; }
        }
      }
      // ballot-compact nonempty segments into wave-private LDS
      unsigned long long mA = __ballot(cnA > 0);
      unsigned long long mB = __ballot(cnB > 0);
      int nA = __popcll(mA);
      int nseg = nA + __popcll(mB);
      if (nseg == 0) continue;
      int slA = lanerank(mA), slB = nA + lanerank(mB);
      if (cnA > 0) { sS[slA] = stA; sC[slA] = cnA; }
      if (cnB > 0) { sS[slB] = stB; sC[slB] = cnB; }
      // exclusive prefix over segment counts (<=128 segs, 2 halves of 64)
      unsigned total = 0;
      for (int h = 0; h < 2; ++h) {
        int sl = h * 64 + lane;
        unsigned v = (sl < nseg) ? sC[sl] : 0u;
        unsigned inc = v;
#pragma unroll
        for (int s2 = 1; s2 < 64; s2 <<= 1) {
          unsigned t = __shfl_up(inc, s2, 64);
          if (lane >= s2) inc += t;
        }
        if (sl < nseg) sPre[sl] = total + inc - v;
        total += __shfl(inc, 63, 64);
        if (nseg <= 64) break;
      }
      // candidates 64-wide across segment boundaries; depth-adaptive search
      int sh0 = (nseg > 1) ? (1 << (31 - __clz(nseg - 1))) : 0;
      for (unsigned cb = 0; cb < total; cb += 64) {
        unsigned c = cb + (unsigned)lane;
        bool cact = c < total;
        unsigned cc = cact ? c : (total - 1);
        int lo = 0;  // max seg with sPre[seg] <= cc (sPre[0]==0)
        for (int sh = sh0; sh; sh >>= 1) {
          int mid = lo + sh;
          if (mid < nseg && sPre[mid] <= cc) lo = mid;
        }
        float4 p = sorted[sS[lo] + (cc - sPre[lo])];
        float d = cact ? sqd3(qx, qy, qz, p) : INFINITY;
        dmin = fminf(dmin, fmaxf(d, a[K - 1]));  // exact evicted-value track
        insertK(a, d);
      }
    }
    // stop test: >= NEED kept candidates within the (tight) bound?
    float bnd = fmaxf((float)m * H + fq, 0.0f) * 0.999f;
    bnd2 = bnd * bnd;
    int c = 0;
#pragma unroll
    for (int k = 0; k < K; ++k) c += (a[k] <= bnd2) ? 1 : 0;
#pragma unroll
    for (int s2 = 1; s2 < 64; s2 <<= 1) c += __shfl_xor(c, s2, 64);
    cnt = c;
    bool covered = (zlo == 0 && zhi == GRID - 1 && ylo == 0 && yhi == GRID - 1 &&
                    xlo == 0 && xhi == GRID - 1);
    if (c >= NEED || covered) break;
  }
}

// ---------- build ----------
// Histogram + per-point (cell, rank): rank from the returning atomic makes
// the scatter atomic-free.
__global__ __launch_bounds__(256) void count_kernel(
    const float* __restrict__ yp, const float* __restrict__ yt,
    unsigned* __restrict__ counts, int* __restrict__ pflat,
    unsigned* __restrict__ prank) {
  int t = blockIdx.x * 256 + threadIdx.x;          // 0 .. 2*NROWS-1
  const float* src;
  int g;
  if (t < NROWS) { src = yp + 3 * t; g = 2 * (t >> 13); }
  else { int u = t - NROWS; src = yt + 3 * u; g = 2 * (u >> 13) + 1; }
  int flat = g * NCELLS + (cellof(src[2]) * GRID + cellof(src[1])) * GRID + cellof(src[0]);
  unsigned r = atomicAdd(&counts[flat], 1u);
  pflat[t] = flat;
  prank[t] = r;
}

// Block-level exclusive scan via wave shfl_up scans (2 barriers; verified in
// R15/R16 -- drop-in replacement for the Hillis-Steele version).
__global__ __launch_bounds__(1024) void scan1_kernel(
    const unsigned* __restrict__ counts, unsigned* __restrict__ partial,
    unsigned* __restrict__ aux) {
  __shared__ unsigned ws[16];
  const int t = threadIdx.x, lane = t & 63, wave = t >> 6;
  const int tid = blockIdx.x * 1024 + t;
  unsigned v = counts[tid];
  unsigned inc = v;                       // inclusive scan within wave
#pragma unroll
  for (int off = 1; off < 64; off <<= 1) {
    unsigned u = __shfl_up(inc, off, 64);
    if (lane >= off) inc += u;
  }
  if (lane == 63) ws[wave] = inc;         // wave totals
  __syncthreads();
  unsigned wex = 0;                       // exclusive scan of 16 wave totals
  if (wave == 0) {
    unsigned o = (lane < 16) ? ws[lane] : 0u;
    unsigned wi = o;
#pragma unroll
    for (int off = 1; off < 16; off <<= 1) {
      unsigned u = __shfl_up(wi, off, 64);
      if (lane >= off) wi += u;
    }
    if (lane < 16) ws[lane] = wi - o;
  }
  __syncthreads();
  wex = ws[wave];
  partial[tid] = wex + inc - v;           // block-exclusive
  if (t == 1023) aux[blockIdx.x] = wex + inc;  // block total
}

// Fused scan2+pack: each block redundantly sums aux[0..blockIdx) (128 vals).
// cellinfo pack: global start (<=16b used of 18) << 14 | count (14b)
__global__ __launch_bounds__(1024) void pack_kernel(
    const unsigned* __restrict__ counts, const unsigned* __restrict__ partial,
    const unsigned* __restrict__ aux, unsigned* __restrict__ pack) {
  __shared__ unsigned sa[2];
  const int t = threadIdx.x;
  if (t < 128) {
    unsigned v = (t < (int)blockIdx.x) ? aux[t] : 0u;
#pragma unroll
    for (int s = 1; s < 64; s <<= 1) v += __shfl_xor(v, s, 64);
    if ((t & 63) == 0) sa[t >> 6] = v;
  }
  __syncthreads();
  unsigned base = sa[0] + sa[1];
  int i = blockIdx.x * 1024 + t;
  pack[i] = ((partial[i] + base) << 14) | counts[i];
}

__global__ __launch_bounds__(256) void scatter_kernel(
    const float* __restrict__ yp, const float* __restrict__ yt,
    const unsigned* __restrict__ pack, const int* __restrict__ pflat,
    const unsigned* __restrict__ prank, float4* __restrict__ sorted) {
  int t = blockIdx.x * 256 + threadIdx.x;
  const float* src;
  int row;
  if (t < NROWS) { row = t; src = yp + 3 * t; }
  else { row = t - NROWS; src = yt + 3 * row; }
  unsigned pos = (pack[pflat[t]] >> 14) + prank[t];
  sorted[pos] = make_float4(src[0], src[1], src[2], __int_as_float(row));
}

// ---------- queries: one wave per query, spatially-sorted order ----------
// wid [0,16384): T point vs P grid  -> knnP row (16 sqrt'd dists) + flag
// wid [16384,32768): T vs T grid    -> knnT row (self included) + flag
// wid [32768,49152): P vs T grid    -> mincol (exact, no flag)
__global__ __launch_bounds__(256) void query_kernel(
    const float4* __restrict__ sorted, const unsigned* __restrict__ pack,
    float* __restrict__ knnP, float* __restrict__ knnT,
    float* __restrict__ mincol_arr, unsigned* __restrict__ flags) {
  __shared__ unsigned sb[4][3][SEGCAP];
  __shared__ float cbw[4][64];
  const int wave = threadIdx.x >> 6, lane = threadIdx.x & 63;
  const int wid = blockIdx.x * 4 + wave;
  const int type = wid >> 14;
  const int qid = wid & 16383;
  const int b = qid >> 13;
  const int src_g = (type == 2) ? 2 * b : 2 * b + 1;
  const int tgt_g = (type == 0) ? 2 * b : 2 * b + 1;
  float4 e = sorted[src_g * NPTS + (qid & (NPTS - 1))];
  const int row = __float_as_int(e.w);
  unsigned* sS = sb[wave][0];
  unsigned* sC = sb[wave][1];
  unsigned* sP = sb[wave][2];
  float* cbuf = cbw[wave];
  if (type < 2) {
    float a[KC];
#pragma unroll
    for (int k = 0; k < KC; ++k) a[k] = INFINITY;
    float dmin = INFINITY, bnd2;
    int cnt;
    wave_grid_knn<KC, KNN>(tgt_g, e.x, e.y, e.z, sorted, pack, sS, sC, sP,
                           lane, a, dmin, cnt, bnd2);
    // Compaction threshold tau (must be >= true v16, with <=64 kept <= tau):
    // cheap path = the verified stop bound when its count is in [16,64];
    // else 16th-smallest lane-min (lane minima are never truncated away).
    float tau;
    if (cnt >= KNN && cnt <= 64) {
      tau = bnd2;
    } else {
      float slm = bitonic_sort64(a[0], lane);
      tau = __shfl(slm, 15, 64);
    }
    int tot = 0;
    int idx[KC];
#pragma unroll
    for (int k = 0; k < KC; ++k) {
      unsigned long long mk = __ballot(a[k] <= tau);
      idx[k] = tot + lanerank(mk);
      tot += __popcll(mk);
    }
#pragma unroll
    for (int k = 0; k < KC; ++k)
      if (a[k] <= tau && idx[k] < 64) cbuf[idx[k]] = a[k];
    float v = (lane < tot) ? cbuf[lane] : INFINITY;  // same-wave: no barrier
    v = bitonic_sort64(v, lane);
    float f15 = __shfl(v, 15, 64);
    // EXACT validity: a lost top-16 member implies dmin <= v16_true <= f15.
    bool bad = (tot > 64) || (__ballot(dmin <= f15) != 0ull);
    float* dst = (type == 0) ? knnP : knnT;
    if (lane < KNN) dst[row * KNN + lane] = sqrtf(v);
    if (lane == 0) flags[type * NROWS + row] = bad ? 1u : 0u;
  } else {
    float a1[1] = {INFINITY};
    float dmin = INFINITY, bnd2;
    int cnt;
    wave_grid_knn<1, 1>(tgt_g, e.x, e.y, e.z, sorted, pack, sS, sC, sP,
                        lane, a1, dmin, cnt, bnd2);
    float v = a1[0];
#pragma unroll
    for (int s = 1; s < 64; s <<= 1) v = fminf(v, __shfl_xor(v, s, 64));
    if (lane == 0) mincol_arr[row] = sqrtf(v);  // lane minima exact
  }
}

// Guaranteed-exact dense fallback over one grid slice (8192 points):
// lane r (r<16) returns the r-th smallest squared distance.
__device__ float exact16_rowlist(const float4* __restrict__ base,
                                 float qx, float qy, float qz, int lane) {
  float a[KNN];
#pragma unroll
  for (int k = 0; k < KNN; ++k) a[k] = INFINITY;
  for (int s = 0; s < NPTS / 64; ++s) {
    float d = sqd3(qx, qy, qz, base[s * 64 + lane]);
    insertK(a, d);
  }
  float res = INFINITY;
#pragma unroll 1
  for (int r = 0; r < KNN; ++r) {
    float v = a[0];
    int idx = lane;
#pragma unroll
    for (int s = 1; s < 64; s <<= 1) {
      float ov = __shfl_xor(v, s, 64);
      int oi = __shfl_xor(idx, s, 64);
      bool take = (ov < v) || (ov == v && oi < idx);
      v = take ? ov : v;
      idx = take ? oi : idx;
    }
    if (lane == r) res = v;
    if (lane == idx) {
#pragma unroll
      for (int k = 0; k < KNN - 1; ++k) a[k] = a[k + 1];
      a[KNN - 1] = INFINITY;
    }
  }
  return res;
}

// Fused tail+combine: each wave repairs flagged rows among its 64 rows
// (expected ~0 per launch: flag needs one lane holding >=7 of a top-16),
// then the block computes deterministic double partials.
__global__ __launch_bounds__(256) void combine_kernel(
    const float* __restrict__ yt, const float4* __restrict__ sorted,
    const unsigned* __restrict__ flags, float* __restrict__ knnP,
    float* __restrict__ knnT, const float* __restrict__ mincol_arr,
    double* __restrict__ pd) {
  __shared__ double s1[256], s2[256], s3[256];
  const int t = threadIdx.x, lane = t & 63, wave = t >> 6;
  const int row0 = blockIdx.x * 256;
  const int rbase = row0 + wave * 64;
  unsigned f0 = flags[rbase + lane];
  unsigned f1 = flags[NROWS + rbase + lane];
  unsigned long long m0 = __ballot(f0 != 0u);
  unsigned long long m1 = __ballot(f1 != 0u);
  while (m0) {                                        // wave-uniform loop
    int rr = __ffsll(m0) - 1; m0 &= m0 - 1;
    int row = rbase + rr;
    int bb = row >> 13;
    const float* q = yt + 3 * row;
    float s = exact16_rowlist(sorted + (size_t)(2 * bb) * NPTS, q[0], q[1], q[2], lane);
    if (lane < KNN) knnP[row * KNN + lane] = sqrtf(s);
  }
  while (m1) {
    int rr = __ffsll(m1) - 1; m1 &= m1 - 1;
    int row = rbase + rr;
    int bb = row >> 13;
    const float* q = yt + 3 * row;
    float s = exact16_rowlist(sorted + (size_t)(2 * bb + 1) * NPTS, q[0], q[1], q[2], lane);
    if (lane < KNN) knnT[row * KNN + lane] = sqrtf(s);
  }
  __syncthreads();  // repairs (global writes by this block) visible block-wide
  const int row = row0 + t;
  float s = 0.0f;
#pragma unroll
  for (int k = 0; k < KNN; ++k)
    s += fabsf(knnP[row * KNN + k] - knnT[row * KNN + k]);
  s1[t] = (double)knnP[row * KNN];   // minrow
  s2[t] = (double)mincol_arr[row];
  s3[t] = (double)s;
  __syncthreads();
  for (int off = 128; off > 0; off >>= 1) {
    if (t < off) { s1[t] += s1[t + off]; s2[t] += s2[t + off]; s3[t] += s3[t + off]; }
    __syncthreads();
  }
  if (t == 0) {
    pd[blockIdx.x * 3 + 0] = s1[0];
    pd[blockIdx.x * 3 + 1] = s2[0];
    pd[blockIdx.x * 3 + 2] = s3[0];
  }
}

__global__ __launch_bounds__(64) void finalize_kernel(
    const double* __restrict__ pd, float* __restrict__ out) {
  const int t = threadIdx.x;
  double a = pd[t * 3], b = pd[t * 3 + 1], c = pd[t * 3 + 2];
#pragma unroll
  for (int s = 32; s >= 1; s >>= 1) {
    a += __shfl_down(a, s, 64);
    b += __shfl_down(b, s, 64);
    c += __shfl_down(c, s, 64);
  }
  if (t == 0) {
    double shape = 0.5 * (a + b) / (double)NROWS;
    double dens = c / ((double)NROWS * KNN);
    out[0] = (float)(shape + dens);
    out[1] = (float)shape;
    out[2] = (float)dens;
  }
}

extern "C" void kernel_launch(void* const* d_in, const int* in_sizes, int n_in,
                              void* d_out, int out_size, void* d_ws, size_t ws_size,
                              hipStream_t stream) {
  (void)in_sizes; (void)n_in; (void)out_size; (void)ws_size;
  const float* yp = (const float*)d_in[0];  // y_pred [B, N, 3]
  const float* yt = (const float*)d_in[1];  // y_true [B, N, 3]
  char* w = (char*)d_ws;
  unsigned* counts  = (unsigned*)w;  w += TOTCELLS * 4;     // 512 KB
  unsigned* partial = (unsigned*)w;  w += TOTCELLS * 4;     // 512 KB
  unsigned* aux     = (unsigned*)w;  w += 512;
  unsigned* pack    = (unsigned*)w;  w += TOTCELLS * 4;     // 512 KB
  int*      pflat   = (int*)w;       w += 2 * NROWS * 4;    // 128 KB
  unsigned* prank   = (unsigned*)w;  w += 2 * NROWS * 4;    // 128 KB
  float4*   sorted  = (float4*)w;    w += 2 * NROWS * 16;   // 1 MB
  float*    knnP    = (float*)w;     w += NROWS * KNN * 4;  // 1 MB
  float*    knnT    = (float*)w;     w += NROWS * KNN * 4;  // 1 MB
  float*    mincol  = (float*)w;     w += NROWS * 4;
  unsigned* flags   = (unsigned*)w;  w += 2 * NROWS * 4;    // written every launch
  double*   pd      = (double*)w;    w += 64 * 3 * 8;
  float* out = (float*)d_out;

  hipMemsetAsync(counts, 0, (size_t)TOTCELLS * 4, stream);
  count_kernel<<<2 * NROWS / 256, 256, 0, stream>>>(yp, yt, counts, pflat, prank);
  scan1_kernel<<<SCAN_BLOCKS, 1024, 0, stream>>>(counts, partial, aux);
  pack_kernel<<<SCAN_BLOCKS, 1024, 0, stream>>>(counts, partial, aux, pack);
  scatter_kernel<<<2 * NROWS / 256, 256, 0, stream>>>(yp, yt, pack, pflat, prank, sorted);
  query_kernel<<<3 * 16384 / 4, 256, 0, stream>>>(sorted, pack, knnP, knnT, mincol, flags);
  combine_kernel<<<64, 256, 0, stream>>>(yt, sorted, flags, knnP, knnT, mincol, pd);
  finalize_kernel<<<1, 64, 0, stream>>>(pd, out);
}